// Round 6
// baseline (7840.401 us; speedup 1.0000x reference)
//
#include <hip/hip_runtime.h>
#include <math.h>

#define B_    64
#define T_    512
#define EMB_  128
#define E_    256
#define H_    384
#define G4_   1536
#define K_    13
#define NG_   12      // unit-groups per dir (32 units each)
#define NCH_  4       // interleaved batch-chains per block (16 batches each)

typedef short s8v  __attribute__((ext_vector_type(8)));
typedef short s4v  __attribute__((ext_vector_type(4)));
typedef float f4v  __attribute__((ext_vector_type(4)));

__device__ __forceinline__ float sigm(float x){ return 1.f/(1.f+__expf(-x)); }
__device__ __forceinline__ float tanh_f(float x){ return 2.f/(1.f+__expf(-2.f*x)) - 1.f; }
__device__ __forceinline__ short f2bf(float x){
  unsigned u = __builtin_bit_cast(unsigned, x);
  return (short)((u + 0x7FFFu + ((u>>16)&1u)) >> 16);
}
__device__ __forceinline__ float bf2f(short s){
  return __builtin_bit_cast(float, ((unsigned)(unsigned short)s) << 16);
}
__device__ __forceinline__ size_t hslotbase(int par, int dir, int q){
  return (size_t)(((par*2 + dir)*NCH_ + q)) * (16*H_);
}

// ---------- K0: pack weights into per-lane MFMA A-fragments (bf16) — unchanged layout
__global__ __launch_bounds__(256) void k_packA(
    const float* __restrict__ wih_f, const float* __restrict__ whh_f,
    const float* __restrict__ wih_b, const float* __restrict__ whh_b,
    s8v* __restrict__ Apack)
{
  int idx = blockIdx.x*256 + threadIdx.x;            // 0..245759
  if (idx >= 2*NG_*8*20*64) return;
  int l   = idx & 63;
  int kt  = (idx>>6) % 20;
  int w   = ((idx>>6)/20) % 8;
  int g   = ((idx>>6)/160) % NG_;
  int dir = (idx>>6)/(160*NG_);
  const float* wih = dir ? wih_b : wih_f;
  const float* whh = dir ? whh_b : whh_f;
  int R = (w>>1)*384 + g*32 + (w&1)*16 + (l&15);
  int kbase = kt*32 + (l>>4)*8;
  const float* src = (kbase < E_) ? (wih + (size_t)R*E_ + kbase)
                                  : (whh + (size_t)R*H_ + (kbase - E_));
  s8v out;
  #pragma unroll
  for (int e = 0; e < 8; e++) out[e] = f2bf(src[e]);
  Apack[idx] = out;
}

// ---------- K1: gather embeddings -> X_all[t][b][256] bf16
__global__ __launch_bounds__(256) void k_embX(
    const int* __restrict__ char_id, const int* __restrict__ bichar_id,
    const float* __restrict__ char_table, const float* __restrict__ bichar_table,
    short* __restrict__ X_all)
{
  int rid  = blockIdx.x*4 + (threadIdx.x>>6);        // 0..32767 = t*64+b
  int lane = threadIdx.x & 63;
  int t = rid >> 6, b = rid & 63;
  float4 v;
  if (lane < 32) { int c = char_id  [b*T_ + t]; v = *(const float4*)(char_table  + (size_t)c*EMB_ + lane*4); }
  else           { int c = bichar_id[b*T_ + t]; v = *(const float4*)(bichar_table+ (size_t)c*EMB_ + (lane-32)*4); }
  s4v o; o[0]=f2bf(v.x); o[1]=f2bf(v.y); o[2]=f2bf(v.z); o[3]=f2bf(v.w);
  *(s4v*)(X_all + ((size_t)rid*E_ + lane*4)) = o;
}

// ---------- K2: persistent-weight MFMA LSTM; 4 interleaved chains hide LLC latency
// 24 blocks: dir=bid&1, g=bid>>1. 512 threads = 8 waves.
__global__ __launch_bounds__(512) void k_lstm_p(
    const s8v* __restrict__ Apack,
    const short* __restrict__ X_all,
    const float* __restrict__ b_f, const float* __restrict__ b_b,
    const float* __restrict__ w_em,
    unsigned* __restrict__ h_slot,       // [2][dir][q][16 b][384 u] u32 = (bf16<<16)|t
    float* __restrict__ em_acc)          // [64][512][13] fp32 (pre-zeroed)
{
  __shared__ short Xs[NCH_][16][648];    // per-chain B operand (x:0..256, h:256..640)
  __shared__ float gl[128][17];          // gate preacts (shared across chains, per sub-period)
  __shared__ float wems[K_][32];
  __shared__ float bsh[128];

  const int bid = blockIdx.x;
  const int dir = bid & 1, g = bid >> 1;
  const int tid = threadIdx.x, lane = tid & 63, w = tid >> 6;

  // persistent A fragments (80 VGPRs)
  s8v frag_a[20];
  {
    const s8v* ap = Apack + ((size_t)((dir*NG_+g)*8 + w)*20)*64 + lane;
    #pragma unroll
    for (int kt = 0; kt < 20; kt++) frag_a[kt] = ap[kt*64];
  }
  if (tid < K_*32) wems[tid>>5][tid&31] = w_em[(size_t)(tid>>5)*(2*H_) + dir*H_ + g*32 + (tid&31)];
  if (tid < 128) {
    const float* bias = dir ? b_b : b_f;
    bsh[tid] = bias[(tid>>5)*H_ + g*32 + (tid&31)];
  }
  float cst0 = 0.f, cst1 = 0.f, cst2 = 0.f, cst3 = 0.f;   // per-chain cell state (static)

  const int uu_n = tid & 31, b_n = tid >> 5;     // (unit, batch) ownership: 32x16 = 512
  const int brow = lane & 15, kch = (lane>>4)*8;
  const int r0 = w*16 + (lane>>4)*4;
  __syncthreads();

  for (int s = 0; s < T_; s++) {
    const int t  = dir ? (T_-1-s) : s;
    const int tp = dir ? t+1 : t-1;
    #pragma unroll
    for (int q = 0; q < NCH_; q++) {
      // ---- A: x-part load (1 s8v/thread) + h poll/unpack (6 u64/thread)
      *(s8v*)&Xs[q][b_n][uu_n*8] =
          *(const s8v*)(X_all + ((size_t)(t*B_ + q*16 + b_n)*E_ + uu_n*8));
      if (s > 0) {
        const unsigned tag = (unsigned)(tp & 0xFFFF);
        const unsigned long long tagpair = (unsigned long long)tag | ((unsigned long long)tag << 32);
        const unsigned long long* hp =
            (const unsigned long long*)(h_slot + hslotbase(tp&1, dir, q)) + ((size_t)b_n*H_ + uu_n*12)/2;
        unsigned long long vals[6];
        unsigned done = 0; int tries = 0;
        while (done != 0x3Fu) {
          #pragma unroll
          for (int i = 0; i < 6; i++) {
            if (!((done >> i) & 1u)) {
              unsigned long long v = __hip_atomic_load(hp + i, __ATOMIC_RELAXED, __HIP_MEMORY_SCOPE_AGENT);
              if (((v ^ tagpair) & 0x0000FFFF0000FFFFull) == 0ull) { vals[i] = v; done |= (1u << i); }
            }
          }
          if (++tries > 2) __builtin_amdgcn_s_sleep(2);   // backoff: cut LLC spin flood
        }
        #pragma unroll
        for (int i = 0; i < 6; i++) {
          unsigned lo = (unsigned)vals[i], hi = (unsigned)(vals[i] >> 32);
          *(unsigned*)&Xs[q][b_n][256 + uu_n*12 + 2*i] = (lo >> 16) | (hi & 0xFFFF0000u);
        }
      } else {
        #pragma unroll
        for (int i = 0; i < 6; i++) *(unsigned*)&Xs[q][b_n][256 + uu_n*12 + 2*i] = 0u;
      }
      __syncthreads();                                    // S1

      // ---- B: 20 MFMA (2 independent accumulators), scatter to gl
      f4v acc0 = {0.f,0.f,0.f,0.f}, acc1 = {0.f,0.f,0.f,0.f};
      #pragma unroll
      for (int kt = 0; kt < 20; kt += 2) {
        s8v bq0 = *(const s8v*)&Xs[q][brow][ kt   *32 + kch];
        s8v bq1 = *(const s8v*)&Xs[q][brow][(kt+1)*32 + kch];
        acc0 = __builtin_amdgcn_mfma_f32_16x16x32_bf16(frag_a[kt],   bq0, acc0, 0,0,0);
        acc1 = __builtin_amdgcn_mfma_f32_16x16x32_bf16(frag_a[kt+1], bq1, acc1, 0,0,0);
      }
      #pragma unroll
      for (int r = 0; r < 4; r++) gl[r0+r][brow] = acc0[r] + acc1[r];
      __syncthreads();                                    // S2

      // ---- C: nonlinearity + tagged publish + emission butterfly (no barrier)
      {
        float gi = gl[      uu_n][b_n] + bsh[      uu_n];
        float gf = gl[ 32 + uu_n][b_n] + bsh[ 32 + uu_n];
        float gg = gl[ 64 + uu_n][b_n] + bsh[ 64 + uu_n];
        float go = gl[ 96 + uu_n][b_n] + bsh[ 96 + uu_n];
        float c_prev = (q==0) ? cst0 : (q==1) ? cst1 : (q==2) ? cst2 : cst3;
        float c_new  = sigm(gf)*c_prev + sigm(gi)*tanh_f(gg);
        if      (q==0) cst0 = c_new;
        else if (q==1) cst1 = c_new;
        else if (q==2) cst2 = c_new;
        else           cst3 = c_new;
        float h = sigm(go)*tanh_f(c_new);
        short hb = f2bf(h);
        unsigned v = ((unsigned)(unsigned short)hb << 16) | (unsigned)(t & 0xFFFF);
        __hip_atomic_store(h_slot + hslotbase(t&1, dir, q) + (size_t)b_n*H_ + g*32 + uu_n,
                           v, __ATOMIC_RELAXED, __HIP_MEMORY_SCOPE_AGENT);
        // emission: for each k, reduce h*wem over the 32 units in this block
        float emk = 0.f;
        #pragma unroll
        for (int k = 0; k < K_; k++) {
          float v2 = h * wems[k][uu_n];
          v2 += __shfl_xor(v2, 1,  64);
          v2 += __shfl_xor(v2, 2,  64);
          v2 += __shfl_xor(v2, 4,  64);
          v2 += __shfl_xor(v2, 8,  64);
          v2 += __shfl_xor(v2, 16, 64);
          if (uu_n == k) emk = v2;
        }
        if (uu_n < K_) atomicAdd(&em_acc[((size_t)(q*16 + b_n)*T_ + t)*K_ + uu_n], emk);
      }
      // no barrier: phase A(q+1) touches Xs[q+1]/polls only; gl rewritten after next S1
    }
  }
}

// ---------- K3: bias + log_softmax in place on em_acc
__global__ __launch_bounds__(256) void k_em2(float* __restrict__ em, const float* __restrict__ b_em){
  int r = blockIdx.x*256 + threadIdx.x;
  float e[K_]; float mx = -1e30f;
  #pragma unroll
  for (int k = 0; k < K_; k++) { e[k] = em[(size_t)r*K_+k] + b_em[k]; mx = fmaxf(mx, e[k]); }
  float S = 0.f;
  #pragma unroll
  for (int k = 0; k < K_; k++) S += __expf(e[k]-mx);
  float L = __logf(S) + mx;
  #pragma unroll
  for (int k = 0; k < K_; k++) em[(size_t)r*K_+k] = e[k] - L;
}

// ---------- K4: CRF gold score + forward algorithm
__global__ __launch_bounds__(64) void k_crf(
    const int* __restrict__ char_id, const int* __restrict__ label_id,
    const float* __restrict__ em,
    const float* __restrict__ start_trans, const float* __restrict__ end_trans,
    const float* __restrict__ trans, float* __restrict__ llh)
{
  int b = blockIdx.x, lane = threadIdx.x;
  const int*   cid = char_id  + b*T_;
  const int*   tag = label_id + b*T_;
  const float* emb = em + (size_t)b*T_*K_;

  float sc = 0.f; int cntm = 0;
  for (int t = lane; t < T_; t += 64) {
    int m = (cid[t] != 0);
    cntm += m;
    if (t >= 1 && m) sc += trans[tag[t-1]*K_ + tag[t]] + emb[t*K_ + tag[t]];
  }
  #pragma unroll
  for (int off = 32; off; off >>= 1) { sc += __shfl_xor(sc, off, 64); cntm += __shfl_xor(cntm, off, 64); }

  __shared__ float alpha[K_];
  __shared__ float scoreSh;
  if (lane == 0) {
    int t0 = tag[0];
    int ce = (cntm > 0) ? (cntm - 1) : 0;
    scoreSh = start_trans[t0] + emb[t0] + sc + end_trans[tag[ce]];
  }
  if (lane < K_) alpha[lane] = start_trans[lane] + emb[lane];
  float tr[K_];
  if (lane < K_) {
    #pragma unroll
    for (int i = 0; i < K_; i++) tr[i] = trans[i*K_ + lane];
  }
  __syncthreads();

  for (int t = 1; t < T_; t++) {
    bool mt = (cid[t] != 0);
    float nxt = 0.f;
    if (lane < K_) {
      float a[K_];
      #pragma unroll
      for (int i = 0; i < K_; i++) a[i] = alpha[i] + tr[i];
      float m = a[0];
      #pragma unroll
      for (int i = 1; i < K_; i++) m = fmaxf(m, a[i]);
      float s2 = 0.f;
      #pragma unroll
      for (int i = 0; i < K_; i++) s2 += __expf(a[i]-m);
      nxt = m + __logf(s2) + emb[t*K_ + lane];
    }
    __syncthreads();
    if (lane < K_ && mt) alpha[lane] = nxt;
    __syncthreads();
  }

  if (lane == 0) {
    float m = alpha[0] + end_trans[0];
    #pragma unroll
    for (int k = 1; k < K_; k++) m = fmaxf(m, alpha[k]+end_trans[k]);
    float s2 = 0.f;
    #pragma unroll
    for (int k = 0; k < K_; k++) s2 += __expf(alpha[k]+end_trans[k]-m);
    llh[b] = scoreSh - (m + __logf(s2));
  }
}

// ---------- K5: out = -mean(llh)
__global__ __launch_bounds__(64) void k_final(const float* __restrict__ llh, float* __restrict__ out){
  float v = llh[threadIdx.x];
  #pragma unroll
  for (int off = 32; off; off >>= 1) v += __shfl_xor(v, off, 64);
  if (threadIdx.x == 0) out[0] = -v / (float)B_;
}

extern "C" void kernel_launch(void* const* d_in, const int* in_sizes, int n_in,
                              void* d_out, int out_size, void* d_ws, size_t ws_size,
                              hipStream_t stream)
{
  const int*   char_id      = (const int*)  d_in[0];
  const int*   bichar_id    = (const int*)  d_in[1];
  const int*   label_id     = (const int*)  d_in[2];
  const float* char_table   = (const float*)d_in[3];
  const float* bichar_table = (const float*)d_in[4];
  const float* w_ih_f       = (const float*)d_in[5];
  const float* w_hh_f       = (const float*)d_in[6];
  const float* b_f          = (const float*)d_in[7];
  const float* w_ih_b       = (const float*)d_in[8];
  const float* w_hh_b       = (const float*)d_in[9];
  const float* b_b          = (const float*)d_in[10];
  const float* w_em         = (const float*)d_in[11];
  const float* b_em         = (const float*)d_in[12];
  const float* start_trans  = (const float*)d_in[13];
  const float* end_trans    = (const float*)d_in[14];
  const float* trans        = (const float*)d_in[15];

  char* w = (char*)d_ws;
  s8v*      Apack  = (s8v*)w;      w += (size_t)2*NG_*8*20*64*16;     // 3,932,160
  short*    X_all  = (short*)w;    w += (size_t)T_*B_*E_*2;           // 16,777,216
  unsigned* h_slot = (unsigned*)w; w += (size_t)2*2*NCH_*16*H_*4;     // 393,216
  float*    em_acc = (float*)w;    w += (size_t)B_*T_*K_*4;           // 1,703,936
  float*    llh    = (float*)w;    w += 256;
  // total ~22.8 MB

  hipMemsetAsync(em_acc, 0, (size_t)B_*T_*K_*4, stream);

  k_packA<<<960, 256, 0, stream>>>(w_ih_f, w_hh_f, w_ih_b, w_hh_b, Apack);
  k_embX <<<8192, 256, 0, stream>>>(char_id, bichar_id, char_table, bichar_table, X_all);
  k_lstm_p<<<24, 512, 0, stream>>>(Apack, X_all, b_f, b_b, w_em, h_slot, em_acc);
  k_em2  <<<128, 256, 0, stream>>>(em_acc, b_em);
  k_crf  <<<64, 64, 0, stream>>>(char_id, label_id, em_acc, start_trans, end_trans, trans, llh);
  k_final<<<1, 64, 0, stream>>>(llh, (float*)d_out);
}

// Round 7
// 2753.846 us; speedup vs baseline: 2.8471x; 2.8471x over previous
//
#include <hip/hip_runtime.h>
#include <math.h>

#define B_    64
#define T_    512
#define EMB_  128
#define E_    256
#define H_    384
#define K_    13
#define NBG   4       // batch groups (16 batches each)
#define NG    6       // unit groups (64 units each)
#define NW    8       // waves per block
#define XROW  1296    // Xs row stride in bytes (648 shorts: 640 used + pad)

typedef short s8v __attribute__((ext_vector_type(8)));
typedef short s4v __attribute__((ext_vector_type(4)));
typedef float f4v __attribute__((ext_vector_type(4)));

__device__ __forceinline__ float sigm(float x){ return 1.f/(1.f+__expf(-x)); }
__device__ __forceinline__ float tanh_f(float x){ return 2.f/(1.f+__expf(-2.f*x)) - 1.f; }
__device__ __forceinline__ short f2bf(float x){
  unsigned u = __builtin_bit_cast(unsigned, x);
  return (short)((u + 0x7FFFu + ((u>>16)&1u)) >> 16);
}
__device__ __forceinline__ float bf2f(short s){
  return __builtin_bit_cast(float, ((unsigned)(unsigned short)s) << 16);
}
// swizzled Xs addressing (T2: xor batch bits into 16B-slot bits to break bank conflicts)
__device__ __forceinline__ void* xsp(char* base, int b, int k){   // k in shorts
  int off = b*XROW + 2*k;
  off ^= (b&7)<<4;
  return (void*)(base + off);
}
__device__ __forceinline__ size_t hslot(int par, int dir, int bg){
  return (size_t)(((par*2 + dir)*NBG + bg)) * (16*H_);
}
__device__ __forceinline__ int fidx(int dir, int bg, int g, int par){
  return ((((dir*NBG+bg)*NG+g)*2)+par)*16;     // 64B-spaced flags
}

// ---------- K0: pack weights into per-lane MFMA A-fragments (bf16)
// set=(dir,g): R_local = w*32+rt*16+(l&15) in [0,256); gate=R_local>>6, ul=R_local&63
// R_glob = gate*384 + g*64 + ul ; k = kt*32+(l>>4)*8+e ; k<256->w_ih, else w_hh
__global__ __launch_bounds__(256) void k_packA(
    const float* __restrict__ wih_f, const float* __restrict__ whh_f,
    const float* __restrict__ wih_b, const float* __restrict__ whh_b,
    s8v* __restrict__ Apack)
{
  int idx = blockIdx.x*256 + threadIdx.x;          // 0..245759
  if (idx >= 12*NW*2*20*64) return;
  int l   = idx & 63;
  int f   = idx >> 6;
  int kt  = f % 20;
  int rt  = (f/20) & 1;
  int w   = (f/40) % NW;
  int set = f/(40*NW);
  int g   = set % NG, dir = set / NG;
  const float* wih = dir ? wih_b : wih_f;
  const float* whh = dir ? whh_b : whh_f;
  int Rl = w*32 + rt*16 + (l&15);
  int Rg = (Rl>>6)*H_ + g*64 + (Rl&63);
  int kb = kt*32 + (l>>4)*8;
  const float* src = (kb < E_) ? (wih + (size_t)Rg*E_ + kb)
                               : (whh + (size_t)Rg*H_ + (kb - E_));
  s8v out;
  #pragma unroll
  for (int e = 0; e < 8; e++) out[e] = f2bf(src[e]);
  Apack[idx] = out;
}

// ---------- K1: gather embeddings -> X_all[t][b][256] bf16
__global__ __launch_bounds__(256) void k_embX(
    const int* __restrict__ char_id, const int* __restrict__ bichar_id,
    const float* __restrict__ char_table, const float* __restrict__ bichar_table,
    short* __restrict__ X_all)
{
  int rid  = blockIdx.x*4 + (threadIdx.x>>6);
  int lane = threadIdx.x & 63;
  int t = rid >> 6, b = rid & 63;
  float4 v;
  if (lane < 32) { int c = char_id  [b*T_ + t]; v = *(const float4*)(char_table  + (size_t)c*EMB_ + lane*4); }
  else           { int c = bichar_id[b*T_ + t]; v = *(const float4*)(bichar_table+ (size_t)c*EMB_ + (lane-32)*4); }
  s4v o; o[0]=f2bf(v.x); o[1]=f2bf(v.y); o[2]=f2bf(v.z); o[3]=f2bf(v.w);
  *(s4v*)(X_all + ((size_t)rid*E_ + lane*4)) = o;
}

// ---------- K2: persistent-weight MFMA LSTM, flag-then-burst h exchange
// 48 blocks: dir=bid&1, bg=(bid>>1)&3, g=bid>>3. 512 threads = 8 waves.
__global__ __launch_bounds__(512) void k_lstm_p(
    const s8v* __restrict__ Apack,
    const short* __restrict__ X_all,
    const float* __restrict__ b_f, const float* __restrict__ b_b,
    const float* __restrict__ w_em,
    unsigned* __restrict__ h_slot,      // [2][dir][bg][16 b][384 u] u32 = (bf16<<16)|t
    unsigned* __restrict__ flags,       // [dir][bg][g][par] (64B-spaced), init 0xFFFFFFFF
    short* __restrict__ em16)           // [48 pb][512 t][16 b][13 k] bf16
{
  __shared__ char  Xsb[16*XROW];        // B operand (x:0..256, h:256..640) swizzled
  __shared__ float gl[256][17];         // gate preacts [gate*64+ul][batch]
  __shared__ short hsl[16][66];         // new h [b][ul] bf16
  __shared__ float wems[K_][64];

  const int bid = blockIdx.x;
  const int dir = bid & 1, bg = (bid>>1)&3, g = bid>>3;
  const int tid = threadIdx.x, lane = tid & 63, w = tid >> 6;
  const int pb  = (dir*NBG+bg)*NG + g;

  // persistent A fragments: 40 s8v = 160 VGPRs
  s8v fr[2][20];
  {
    const s8v* ap = Apack + ((size_t)((dir*NG+g)*NW + w)*40)*64 + lane;
    #pragma unroll
    for (int rt = 0; rt < 2; rt++)
      #pragma unroll
      for (int kt = 0; kt < 20; kt++) fr[rt][kt] = ap[(rt*20+kt)*64];
  }
  for (int i = tid; i < K_*64; i += 512)
    wems[i>>6][i&63] = w_em[(size_t)(i>>6)*(2*H_) + dir*H_ + g*64 + (i&63)];

  const int ul = tid>>3, b2 = (tid&7)*2;          // nonlinearity ownership
  const float* bias = dir ? b_b : b_f;
  float bi0 = bias[        g*64 + ul];
  float bi1 = bias[  H_  + g*64 + ul];
  float bi2 = bias[2*H_  + g*64 + ul];
  float bi3 = bias[3*H_  + g*64 + ul];
  float cA = 0.f, cB = 0.f;

  const int brow = lane & 15, kch = (lane>>4)*8;
  const int b_r = tid>>5, ch = tid&31;            // burst ownership: 16b x 32 chunks(12u)
  __syncthreads();

  for (int s = 0; s < T_; s++) {
    const int t  = dir ? (T_-1-s) : s;
    const int tp = dir ? t+1 : t-1;

    // ---- A1: x-part -> Xs (issue early; overlaps flag wait)
    { int b = tid>>5, ko = (tid&31)*8;
      *(s8v*)xsp(Xsb, b, ko) = *(const s8v*)(X_all + ((size_t)(t*B_ + bg*16 + b)*E_ + ko)); }

    if (s > 0) {
      // ---- flag wait: 6 pollers, one flag each
      if (tid < NG) {
        const unsigned* fp = flags + fidx(dir, bg, tid, tp&1);
        while (__hip_atomic_load(fp, __ATOMIC_RELAXED, __HIP_MEMORY_SCOPE_AGENT) != (unsigned)tp)
          __builtin_amdgcn_s_sleep(1);
      }
      __syncthreads();                            // S0
      // ---- burst: 6 u64 tagged loads, single shot (flag guarantees), fallback loop
      const unsigned tag = (unsigned)(tp & 0xFFFF);
      const unsigned long long tagpair = (unsigned long long)tag | ((unsigned long long)tag << 32);
      const unsigned long long* hp =
          (const unsigned long long*)(h_slot + hslot(tp&1, dir, bg)) + ((size_t)b_r*H_ + ch*12)/2;
      unsigned long long vals[6];
      unsigned done = 0;
      while (done != 0x3Fu) {
        #pragma unroll
        for (int i = 0; i < 6; i++) {
          if (!((done >> i) & 1u)) {
            unsigned long long v = __hip_atomic_load(hp + i, __ATOMIC_RELAXED, __HIP_MEMORY_SCOPE_AGENT);
            if (((v ^ tagpair) & 0x0000FFFF0000FFFFull) == 0ull) { vals[i] = v; done |= (1u << i); }
          }
        }
      }
      #pragma unroll
      for (int i = 0; i < 6; i++) {
        unsigned lo = (unsigned)vals[i], hi = (unsigned)(vals[i] >> 32);
        *(unsigned*)xsp(Xsb, b_r, 256 + ch*12 + 2*i) = (lo >> 16) | (hi & 0xFFFF0000u);
      }
    } else {
      #pragma unroll
      for (int i = 0; i < 6; i++) *(unsigned*)xsp(Xsb, b_r, 256 + ch*12 + 2*i) = 0u;
    }
    __syncthreads();                              // S1

    // ---- B: 40 MFMA, 4 accumulators for dep-distance
    f4v a00={0.f,0.f,0.f,0.f}, a01=a00, a10=a00, a11=a00;
    #pragma unroll
    for (int kt = 0; kt < 20; kt += 2) {
      s8v q0 = *(const s8v*)xsp(Xsb, brow,  kt   *32 + kch);
      s8v q1 = *(const s8v*)xsp(Xsb, brow, (kt+1)*32 + kch);
      a00 = __builtin_amdgcn_mfma_f32_16x16x32_bf16(fr[0][kt],   q0, a00, 0,0,0);
      a10 = __builtin_amdgcn_mfma_f32_16x16x32_bf16(fr[1][kt],   q0, a10, 0,0,0);
      a01 = __builtin_amdgcn_mfma_f32_16x16x32_bf16(fr[0][kt+1], q1, a01, 0,0,0);
      a11 = __builtin_amdgcn_mfma_f32_16x16x32_bf16(fr[1][kt+1], q1, a11, 0,0,0);
    }
    {
      int r0 = w*32 + (lane>>4)*4;
      #pragma unroll
      for (int r = 0; r < 4; r++) {
        gl[r0+r   ][brow] = a00[r] + a01[r];
        gl[r0+16+r][brow] = a10[r] + a11[r];
      }
    }
    __syncthreads();                              // S2

    // ---- C: nonlinearity (2 batches per thread) + tagged publish + hsl
    {
      unsigned* hw = h_slot + hslot(t&1, dir, bg);
      int uglob = g*64 + ul;
      float gi = gl[     ul][b2] + bi0, gf = gl[ 64+ul][b2] + bi1;
      float gg = gl[128+ul][b2] + bi2, go = gl[192+ul][b2] + bi3;
      cA = sigm(gf)*cA + sigm(gi)*tanh_f(gg);
      float h0 = sigm(go)*tanh_f(cA);
      gi = gl[     ul][b2+1] + bi0; gf = gl[ 64+ul][b2+1] + bi1;
      gg = gl[128+ul][b2+1] + bi2; go = gl[192+ul][b2+1] + bi3;
      cB = sigm(gf)*cB + sigm(gi)*tanh_f(gg);
      float h1 = sigm(go)*tanh_f(cB);
      short hb0 = f2bf(h0), hb1 = f2bf(h1);
      unsigned vt = (unsigned)(t & 0xFFFF);
      __hip_atomic_store(hw + (size_t)b2    *H_ + uglob,
                         ((unsigned)(unsigned short)hb0 << 16) | vt,
                         __ATOMIC_RELAXED, __HIP_MEMORY_SCOPE_AGENT);
      __hip_atomic_store(hw + (size_t)(b2+1)*H_ + uglob,
                         ((unsigned)(unsigned short)hb1 << 16) | vt,
                         __ATOMIC_RELAXED, __HIP_MEMORY_SCOPE_AGENT);
      hsl[b2  ][ul] = hb0;
      hsl[b2+1][ul] = hb1;
    }
    __syncthreads();                              // S3 (drains all waves' stores)

    // ---- publish flag (stores provably at LLC), then emission partials
    if (tid == 0)
      __hip_atomic_store(flags + fidx(dir, bg, g, t&1), (unsigned)t,
                         __ATOMIC_RELAXED, __HIP_MEMORY_SCOPE_AGENT);

    for (int k = w; k < K_; k += NW) {
      int b = lane>>2, cq = lane&3;
      float acc = 0.f;
      #pragma unroll
      for (int m = 0; m < 8; m++) {
        int u = cq*16 + 2*m;
        unsigned pr = *(const unsigned*)&hsl[b][u];
        acc += bf2f((short)(pr & 0xFFFF)) * wems[k][u]
             + bf2f((short)(pr >> 16))    * wems[k][u+1];
      }
      acc += __shfl_xor(acc, 1, 64);
      acc += __shfl_xor(acc, 2, 64);
      if (cq == 0) em16[((size_t)(pb*T_ + t)*16 + b)*K_ + k] = f2bf(acc);
    }
  }
}

// ---------- K3: combine 12 partials + bias, log_softmax -> em_out
__global__ __launch_bounds__(256) void k_em2(
    const short* __restrict__ em16, const float* __restrict__ b_em,
    float* __restrict__ em)
{
  int r = blockIdx.x*256 + threadIdx.x;           // b*512 + t
  int b = r >> 9, t = r & 511;
  int bg = b >> 4, b16 = b & 15;
  float e[K_];
  #pragma unroll
  for (int k = 0; k < K_; k++) e[k] = b_em[k];
  #pragma unroll
  for (int dir = 0; dir < 2; dir++)
    for (int g = 0; g < NG; g++) {
      int pb = (dir*NBG+bg)*NG + g;
      const short* p = em16 + ((size_t)(pb*T_ + t)*16 + b16)*K_;
      #pragma unroll
      for (int k = 0; k < K_; k++) e[k] += bf2f(p[k]);
    }
  float mx = -1e30f;
  #pragma unroll
  for (int k = 0; k < K_; k++) mx = fmaxf(mx, e[k]);
  float S = 0.f;
  #pragma unroll
  for (int k = 0; k < K_; k++) S += __expf(e[k]-mx);
  float L = __logf(S) + mx;
  #pragma unroll
  for (int k = 0; k < K_; k++) em[(size_t)r*K_+k] = e[k] - L;
}

// ---------- K4: CRF gold score + forward algorithm
__global__ __launch_bounds__(64) void k_crf(
    const int* __restrict__ char_id, const int* __restrict__ label_id,
    const float* __restrict__ em,
    const float* __restrict__ start_trans, const float* __restrict__ end_trans,
    const float* __restrict__ trans, float* __restrict__ llh)
{
  int b = blockIdx.x, lane = threadIdx.x;
  const int*   cid = char_id  + b*T_;
  const int*   tag = label_id + b*T_;
  const float* emb = em + (size_t)b*T_*K_;

  float sc = 0.f; int cntm = 0;
  for (int t = lane; t < T_; t += 64) {
    int m = (cid[t] != 0);
    cntm += m;
    if (t >= 1 && m) sc += trans[tag[t-1]*K_ + tag[t]] + emb[t*K_ + tag[t]];
  }
  #pragma unroll
  for (int off = 32; off; off >>= 1) { sc += __shfl_xor(sc, off, 64); cntm += __shfl_xor(cntm, off, 64); }

  __shared__ float alpha[K_];
  __shared__ float scoreSh;
  if (lane == 0) {
    int t0 = tag[0];
    int ce = (cntm > 0) ? (cntm - 1) : 0;
    scoreSh = start_trans[t0] + emb[t0] + sc + end_trans[tag[ce]];
  }
  if (lane < K_) alpha[lane] = start_trans[lane] + emb[lane];
  float tr[K_];
  if (lane < K_) {
    #pragma unroll
    for (int i = 0; i < K_; i++) tr[i] = trans[i*K_ + lane];
  }
  __syncthreads();

  for (int t = 1; t < T_; t++) {
    bool mt = (cid[t] != 0);
    float nxt = 0.f;
    if (lane < K_) {
      float a[K_];
      #pragma unroll
      for (int i = 0; i < K_; i++) a[i] = alpha[i] + tr[i];
      float m = a[0];
      #pragma unroll
      for (int i = 1; i < K_; i++) m = fmaxf(m, a[i]);
      float s2 = 0.f;
      #pragma unroll
      for (int i = 0; i < K_; i++) s2 += __expf(a[i]-m);
      nxt = m + __logf(s2) + emb[t*K_ + lane];
    }
    __syncthreads();
    if (lane < K_ && mt) alpha[lane] = nxt;
    __syncthreads();
  }

  if (lane == 0) {
    float m = alpha[0] + end_trans[0];
    #pragma unroll
    for (int k = 1; k < K_; k++) m = fmaxf(m, alpha[k]+end_trans[k]);
    float s2 = 0.f;
    #pragma unroll
    for (int k = 0; k < K_; k++) s2 += __expf(alpha[k]+end_trans[k]-m);
    llh[b] = scoreSh - (m + __logf(s2));
  }
}

// ---------- K5: out = -mean(llh)
__global__ __launch_bounds__(64) void k_final(const float* __restrict__ llh, float* __restrict__ out){
  float v = llh[threadIdx.x];
  #pragma unroll
  for (int off = 32; off; off >>= 1) v += __shfl_xor(v, off, 64);
  if (threadIdx.x == 0) out[0] = -v / (float)B_;
}

extern "C" void kernel_launch(void* const* d_in, const int* in_sizes, int n_in,
                              void* d_out, int out_size, void* d_ws, size_t ws_size,
                              hipStream_t stream)
{
  const int*   char_id      = (const int*)  d_in[0];
  const int*   bichar_id    = (const int*)  d_in[1];
  const int*   label_id     = (const int*)  d_in[2];
  const float* char_table   = (const float*)d_in[3];
  const float* bichar_table = (const float*)d_in[4];
  const float* w_ih_f       = (const float*)d_in[5];
  const float* w_hh_f       = (const float*)d_in[6];
  const float* b_f          = (const float*)d_in[7];
  const float* w_ih_b       = (const float*)d_in[8];
  const float* w_hh_b       = (const float*)d_in[9];
  const float* b_b          = (const float*)d_in[10];
  const float* w_em         = (const float*)d_in[11];
  const float* b_em         = (const float*)d_in[12];
  const float* start_trans  = (const float*)d_in[13];
  const float* end_trans    = (const float*)d_in[14];
  const float* trans        = (const float*)d_in[15];

  char* w = (char*)d_ws;
  s8v*      Apack  = (s8v*)w;      w += (size_t)12*NW*2*20*64*16;    //  3,932,160
  short*    X_all  = (short*)w;    w += (size_t)T_*B_*E_*2;          // 16,777,216
  unsigned* h_slot = (unsigned*)w; w += (size_t)2*2*NBG*16*H_*4;     //    393,216
  unsigned* flags  = (unsigned*)w; w += (size_t)2*NBG*NG*2*16*4;     //      6,144
  short*    em16   = (short*)w;    w += (size_t)48*T_*16*K_*2;       // 10,223,616
  float*    em_out = (float*)w;    w += (size_t)B_*T_*K_*4;          //  1,703,936
  float*    llh    = (float*)w;    w += 256;
  // total ~33.0 MB

  hipMemsetAsync(h_slot, 0xFF, (size_t)2*2*NBG*16*H_*4 + (size_t)2*NBG*NG*2*16*4, stream);

  k_packA<<<960, 256, 0, stream>>>(w_ih_f, w_hh_f, w_ih_b, w_hh_b, Apack);
  k_embX <<<8192, 256, 0, stream>>>(char_id, bichar_id, char_table, bichar_table, X_all);
  k_lstm_p<<<48, 512, 0, stream>>>(Apack, X_all, b_f, b_b, w_em, h_slot, flags, em16);
  k_em2  <<<128, 256, 0, stream>>>(em16, b_em, em_out);
  k_crf  <<<64, 64, 0, stream>>>(char_id, label_id, em_out, start_trans, end_trans, trans, llh);
  k_final<<<1, 64, 0, stream>>>(llh, (float*)d_out);
}